// Round 18
// baseline (337.881 us; speedup 1.0000x reference)
//
#include <hip/hip_runtime.h>
#include <hip/hip_bf16.h>

typedef __attribute__((ext_vector_type(8))) short short8;
typedef __attribute__((ext_vector_type(4))) float f32x4;
typedef __attribute__((ext_vector_type(4))) unsigned short u16x4;
typedef unsigned short u16;

#define Bn 8
#define Tn 2048
#define Cn 1024
#define Hn 64
#define Mrows (Bn * Tn)  // 16384

__device__ __forceinline__ u16 bfu(float f) {
    __hip_bfloat16 h = __float2bfloat16(f);
    union { __hip_bfloat16 h; u16 u; } c; c.h = h; return c.u;
}

__device__ __forceinline__ short8 cvt8(f32x4 a0, f32x4 a1) {
    short8 r;
    r[0] = (short)bfu(a0[0]); r[1] = (short)bfu(a0[1]);
    r[2] = (short)bfu(a0[2]); r[3] = (short)bfu(a0[3]);
    r[4] = (short)bfu(a1[0]); r[5] = (short)bfu(a1[1]);
    r[6] = (short)bfu(a1[2]); r[7] = (short)bfu(a1[3]);
    return r;
}

// W [1024][64] f32 x3 -> wtf fragment-linear bf16 (round-9 layout).
__global__ void convert_w3(const float* __restrict__ Wq, const float* __restrict__ Wk,
                           const float* __restrict__ Wv, u16* __restrict__ wtf, float qscale) {
    int widx = blockIdx.x * 256 + threadIdx.x;          // 0 .. 196607
    int mat = widx >> 16;
    int rem = widx & 65535;
    int k = rem >> 6, n = rem & 63;
    const float* W = mat == 0 ? Wq : (mat == 1 ? Wk : Wv);
    float s = mat == 0 ? qscale : 1.0f;
    int ct = mat * 4 + (n >> 4);
    int lane = ((k >> 3) & 3) * 16 + (n & 15);
    wtf[(size_t)(ct * 32 + (k >> 5)) * 512 + lane * 8 + (k & 7)] = bfu(W[rem] * s);
}

// MEASUREMENT ROUND (2nd instrumentation pass): grid x16; blocks with the same
// (bid & 511) redo identical work -> dispatch ~= 16*Q, guaranteed top-5 with
// PMC. Round-17 postmortem: cross-round algebra for Q is contradictory
// (4 vs 25 us); this pins it directly.
__global__ __launch_bounds__(512) void qkv_proj(const float* __restrict__ x,
                                                const u16* __restrict__ wtf,
                                                u16* __restrict__ qfl,
                                                u16* __restrict__ kfl,
                                                u16* __restrict__ vfl) {
    __shared__ u16 As[2][32][136];
    const int tid = threadIdx.x;
    const int lane = tid & 63;
    const int wid = tid >> 6;         // 0..7
    const int wm = wid >> 2;          // 0..1 -> 16-row slice
    const int wn = wid & 3;           // 0..3 -> 48-col slice
    const int l15 = lane & 15;
    const int lhi = lane >> 4;
    const int row0 = ((int)blockIdx.x & 511) * 32;

    const int arow = tid >> 4;        // 0..31
    const int ac0 = (tid & 15) * 8;   // f32 col 0..120
    const float* asrc = x + (size_t)(row0 + arow) * Cn + ac0;

    f32x4 acc[3];
    for (int nj = 0; nj < 3; ++nj) acc[nj] = f32x4{0.f, 0.f, 0.f, 0.f};

    f32x4 r0 = *(const f32x4*)(asrc);
    f32x4 r1 = *(const f32x4*)(asrc + 4);
    *(short8*)&As[0][arow][ac0] = cvt8(r0, r1);
    r0 = *(const f32x4*)(asrc + 128);
    r1 = *(const f32x4*)(asrc + 132);
    __syncthreads();

    for (int ks = 0; ks < 8; ++ks) {
        const int cur = ks & 1;
        if (ks < 7) {
            *(short8*)&As[cur ^ 1][arow][ac0] = cvt8(r0, r1);
            if (ks < 6) {
                const float* nsrc = asrc + (size_t)(ks + 2) * 128;
                r0 = *(const f32x4*)(nsrc);
                r1 = *(const f32x4*)(nsrc + 4);
            }
        }
        #pragma unroll
        for (int kc = 0; kc < 4; ++kc) {
            short8 af = *(const short8*)&As[cur][wm * 16 + l15][kc * 32 + lhi * 8];
            #pragma unroll
            for (int nj = 0; nj < 3; ++nj) {
                short8 bf = *(const short8*)(wtf + (size_t)((wn * 3 + nj) * 32 + ks * 4 + kc) * 512 + lane * 8);
                acc[nj] = __builtin_amdgcn_mfma_f32_16x16x32_bf16(af, bf, acc[nj], 0, 0, 0);
            }
        }
        __syncthreads();
    }

    const int growb = row0 + wm * 16 + lhi * 4;        // t = growb + r
    const int bI = growb >> 11;
    const int tloc = growb & 2047;
    #pragma unroll
    for (int nj = 0; nj < 3; ++nj) {
        const int gcolb = wn * 48 + nj * 16;
        const int matid = gcolb >> 6;
        const int d0 = gcolb & 63;
        if (matid < 2) {
            u16* dst = matid == 0 ? qfl : kfl;
            const int g = tloc >> 4;
            const int lhid = ((d0 & 31) + l15) >> 3;
            const size_t base = ((size_t)(bI * 128 + g) * 2 + (d0 >> 5)) * 512
                                + (size_t)lhid * 128 + (l15 & 7);
            for (int r = 0; r < 4; ++r)
                dst[base + (size_t)(lhi * 4 + r) * 8] = bfu(acc[nj][r]);
        } else {
            const int kt64 = tloc >> 6;
            const int tin = tloc & 63;
            const int kcv = tin >> 5;
            const int lhiv = (tin & 31) >> 3;
            const int e0 = tin & 7;
            const int dt = d0 >> 4;
            u16x4 pk;
            pk[0] = bfu(acc[nj][0]); pk[1] = bfu(acc[nj][1]);
            pk[2] = bfu(acc[nj][2]); pk[3] = bfu(acc[nj][3]);
            *(u16x4*)(vfl + ((size_t)((bI * 32 + kt64) * 4 + dt) * 2 + kcv) * 512
                          + (size_t)(lhiv * 16 + l15) * 8 + e0) = pk;
        }
    }
}

// MEASUREMENT ROUND: grid x4; blocks with same (bid & 1023) redo identical
// work -> dispatch ~= 4*A, visible in top-5 with PMC. (Round-17 structure:
// 8 waves/q-tile, block-level split-K, LDS combine.)
__global__ __launch_bounds__(512, 4) void attn_fwd(const u16* __restrict__ qfl,
                                                   const u16* __restrict__ kfl,
                                                   const u16* __restrict__ vfl,
                                                   float* __restrict__ out) {
    __shared__ float o_lds[8][16][68];
    __shared__ float ml_lds[8][2][16];
    __shared__ u16 pl[8][16][72];
    const int tid = threadIdx.x;
    const int lane = tid & 63;
    const int w = tid >> 6;           // 0..7
    const int l15 = lane & 15, lhi = lane >> 4;
    const int idx = (int)blockIdx.x & 1023;
    const int qt = 127 - (idx >> 3);  // longest q-tiles dispatched first
    const int b = idx & 7;
    const int nkt = (qt >> 2) + 1;
    const int q0 = qt * 16;

    const u16* qb = qfl + (size_t)b * 131072;
    const u16* kb = kfl + (size_t)b * 131072;
    const u16* vb = vfl + (size_t)b * 131072;

    short8 qf[2];
    #pragma unroll
    for (int kc = 0; kc < 2; ++kc)
        qf[kc] = *(const short8*)(qb + ((size_t)(qt * 2 + kc) * 64 + lane) * 8);

    float m = -1e30f, lpart = 0.f;
    f32x4 o[4];
    for (int dt = 0; dt < 4; ++dt) o[dt] = f32x4{0.f, 0.f, 0.f, 0.f};

    for (int kbi = w; kbi < nkt; kbi += 8) {
        const int k0 = kbi * 64;
        short8 kf[2][4], vf[4][2];
        #pragma unroll
        for (int kc = 0; kc < 2; ++kc)
            #pragma unroll
            for (int kt = 0; kt < 4; ++kt)
                kf[kc][kt] = *(const short8*)(kb + ((size_t)((kbi * 4 + kt) * 2 + kc) * 64 + lane) * 8);
        #pragma unroll
        for (int dt = 0; dt < 4; ++dt)
            #pragma unroll
            for (int kc = 0; kc < 2; ++kc)
                vf[dt][kc] = *(const short8*)(vb + ((size_t)((kbi * 4 + dt) * 2 + kc) * 512 + lane * 8));

        f32x4 sacc[4];
        for (int kt = 0; kt < 4; ++kt) sacc[kt] = f32x4{0.f, 0.f, 0.f, 0.f};
        #pragma unroll
        for (int kc = 0; kc < 2; ++kc)
            #pragma unroll
            for (int kt = 0; kt < 4; ++kt)
                sacc[kt] = __builtin_amdgcn_mfma_f32_16x16x32_bf16(kf[kc][kt], qf[kc], sacc[kt], 0, 0, 0);

        if (kbi == nkt - 1) {             // diagonal: causal mask
            for (int kt = 0; kt < 4; ++kt)
                for (int r = 0; r < 4; ++r) {
                    int kg = k0 + kt * 16 + lhi * 4 + r;
                    if (kg > q0 + l15) sacc[kt][r] = -3.0e38f;
                }
        }
        f32x4 mx0, mx1;
        for (int e = 0; e < 4; ++e) {
            mx0[e] = fmaxf(sacc[0][e], sacc[1][e]);
            mx1[e] = fmaxf(sacc[2][e], sacc[3][e]);
        }
        float tmax = -3.0e38f;
        for (int e = 0; e < 4; ++e) tmax = fmaxf(tmax, fmaxf(mx0[e], mx1[e]));
        tmax = fmaxf(tmax, __shfl_xor(tmax, 16));
        tmax = fmaxf(tmax, __shfl_xor(tmax, 32));
        if (!__all(tmax <= m + 8.0f)) {   // defer-max (THR=8, log2 domain)
            float mnew = fmaxf(m, tmax);
            float corr = exp2f(m - mnew);
            m = mnew;
            lpart *= corr;
            for (int r = 0; r < 4; ++r) {
                float cr = __shfl(corr, lhi * 4 + r);
                for (int dt = 0; dt < 4; ++dt) o[dt][r] *= cr;
            }
        }
        float psum = 0.f;
        for (int kt = 0; kt < 4; ++kt)
            for (int r = 0; r < 4; ++r) {
                float p = exp2f(sacc[kt][r] - m);
                sacc[kt][r] = p;
                psum += p;
            }
        lpart += psum;
        for (int kt = 0; kt < 4; ++kt) {
            u16x4 pk;
            pk[0] = bfu(sacc[kt][0]); pk[1] = bfu(sacc[kt][1]);
            pk[2] = bfu(sacc[kt][2]); pk[3] = bfu(sacc[kt][3]);
            *(u16x4*)&pl[w][l15][kt * 16 + lhi * 4] = pk;
        }
        short8 pf[2];
        #pragma unroll
        for (int kc = 0; kc < 2; ++kc)
            pf[kc] = *(const short8*)&pl[w][l15][kc * 32 + lhi * 8];
        #pragma unroll
        for (int dt = 0; dt < 4; ++dt)
            #pragma unroll
            for (int kc = 0; kc < 2; ++kc)
                o[dt] = __builtin_amdgcn_mfma_f32_16x16x32_bf16(pf[kc], vf[dt][kc], o[dt], 0, 0, 0);
    }
    float lsum = lpart;
    lsum += __shfl_xor(lsum, 16);
    lsum += __shfl_xor(lsum, 32);

    for (int dt = 0; dt < 4; ++dt)
        for (int r = 0; r < 4; ++r)
            o_lds[w][lhi * 4 + r][dt * 16 + l15] = o[dt][r];
    if (lhi == 0) {
        ml_lds[w][0][l15] = m;
        ml_lds[w][1][l15] = lsum;
    }
    __syncthreads();

    float* ob = out + ((size_t)b * Tn + q0) * Hn;
    #pragma unroll
    for (int i = 0; i < 2; ++i) {
        const int e = tid + 512 * i;      // 0..1023
        const int row = e >> 6, d = e & 63;
        float M = -3.0e38f;
        #pragma unroll
        for (int ww = 0; ww < 8; ++ww) M = fmaxf(M, ml_lds[ww][0][row]);
        float L = 0.f, acc = 0.f;
        #pragma unroll
        for (int ww = 0; ww < 8; ++ww) {
            float wgt = exp2f(ml_lds[ww][0][row] - M);
            L += ml_lds[ww][1][row] * wgt;
            acc += o_lds[ww][row][d] * wgt;
        }
        ob[(size_t)row * Hn + d] = acc / L;
    }
}

extern "C" void kernel_launch(void* const* d_in, const int* in_sizes, int n_in,
                              void* d_out, int out_size, void* d_ws, size_t ws_size,
                              hipStream_t stream) {
    const float* x = (const float*)d_in[0];
    const float* Wq = (const float*)d_in[1];
    const float* Wk = (const float*)d_in[2];
    const float* Wv = (const float*)d_in[3];
    float* out = (float*)d_out;
    char* ws = (char*)d_ws;

    u16* wtf = (u16*)ws;                                   // 384 KB
    u16* qfl = (u16*)(ws + 196608 * 2);                    // 2 MB
    u16* kfl = qfl + (size_t)Bn * 131072;                  // 2 MB
    u16* vfl = kfl + (size_t)Bn * 131072;                  // 2 MB

    const float qscale = 0.04508422002778011f;  // C^-0.5 * log2(e)
    convert_w3<<<768, 256, 0, stream>>>(Wq, Wk, Wv, wtf, qscale);
    // MEASUREMENT: qkv x16 in one dispatch, attn x4 in one dispatch.
    // Q = qkv_dispatch_dur/16, A = attn_dispatch_dur/4, both with full PMC.
    qkv_proj<<<8192, 512, 0, stream>>>(x, wtf, qfl, kfl, vfl);
    attn_fwd<<<4096, 512, 0, stream>>>(qfl, kfl, vfl, out);
}

// Round 19
// 47.514 us; speedup vs baseline: 7.1111x; 7.1111x over previous
//
#include <hip/hip_runtime.h>
#include <hip/hip_bf16.h>

typedef __attribute__((ext_vector_type(8))) short short8;
typedef __attribute__((ext_vector_type(4))) float f32x4;
typedef __attribute__((ext_vector_type(4))) unsigned short u16x4;
typedef unsigned short u16;

#define Bn 8
#define Tn 2048
#define Cn 1024
#define Hn 64
#define Mrows (Bn * Tn)  // 16384

__device__ __forceinline__ u16 bfu(float f) {
    __hip_bfloat16 h = __float2bfloat16(f);
    union { __hip_bfloat16 h; u16 u; } c; c.h = h; return c.u;
}

__device__ __forceinline__ short8 cvt8(f32x4 a0, f32x4 a1) {
    short8 r;
    r[0] = (short)bfu(a0[0]); r[1] = (short)bfu(a0[1]);
    r[2] = (short)bfu(a0[2]); r[3] = (short)bfu(a0[3]);
    r[4] = (short)bfu(a1[0]); r[5] = (short)bfu(a1[1]);
    r[6] = (short)bfu(a1[2]); r[7] = (short)bfu(a1[3]);
    return r;
}

// W [1024][64] f32 x3 -> wtf fragment-linear bf16 (round-9 layout).
__global__ void convert_w3(const float* __restrict__ Wq, const float* __restrict__ Wk,
                           const float* __restrict__ Wv, u16* __restrict__ wtf, float qscale) {
    int widx = blockIdx.x * 256 + threadIdx.x;          // 0 .. 196607
    int mat = widx >> 16;
    int rem = widx & 65535;
    int k = rem >> 6, n = rem & 63;
    const float* W = mat == 0 ? Wq : (mat == 1 ? Wk : Wv);
    float s = mat == 0 ? qscale : 1.0f;
    int ct = mat * 4 + (n >> 4);
    int lane = ((k >> 3) & 3) * 16 + (n & 15);
    wtf[(size_t)(ct * 32 + (k >> 5)) * 512 + lane * 8 + (k & 7)] = bfu(W[rem] * s);
}

// x [16384][1024] f32 @ W -> q/k/v fragment-linear.
// Round-18 postmortem: qkv is L2-BW bound; the 8-wave v4 read each B-frag
// TWICE per block (393 MB L2). This is v3's dataflow (4 waves, distinct wn,
// acc[2][3] -> every B-frag read exactly once per block, 196 MB) combined
// with v4's double-buffered LDS A (one barrier per K-step).
__global__ __launch_bounds__(256, 4) void qkv_proj(const float* __restrict__ x,
                                                   const u16* __restrict__ wtf,
                                                   u16* __restrict__ qfl,
                                                   u16* __restrict__ kfl,
                                                   u16* __restrict__ vfl) {
    __shared__ u16 As[2][32][136];
    const int tid = threadIdx.x;
    const int lane = tid & 63;
    const int wn = tid >> 6;          // 0..3 -> 48-col slice (distinct per wave)
    const int l15 = lane & 15;
    const int lhi = lane >> 4;
    const int row0 = blockIdx.x * 32;

    const int arow = tid >> 3;        // 0..31
    const int ac0 = (tid & 7) * 16;   // f32 col base 0..112 (16 f32/thread)
    const float* asrc = x + (size_t)(row0 + arow) * Cn + ac0;

    f32x4 acc[2][3];
    for (int mt = 0; mt < 2; ++mt)
        for (int nj = 0; nj < 3; ++nj) acc[mt][nj] = f32x4{0.f, 0.f, 0.f, 0.f};

    // prologue: buf0 <- ks0; regs <- ks1
    f32x4 r0 = *(const f32x4*)(asrc);
    f32x4 r1 = *(const f32x4*)(asrc + 4);
    f32x4 r2 = *(const f32x4*)(asrc + 8);
    f32x4 r3 = *(const f32x4*)(asrc + 12);
    *(short8*)&As[0][arow][ac0]     = cvt8(r0, r1);
    *(short8*)&As[0][arow][ac0 + 8] = cvt8(r2, r3);
    r0 = *(const f32x4*)(asrc + 128);
    r1 = *(const f32x4*)(asrc + 132);
    r2 = *(const f32x4*)(asrc + 136);
    r3 = *(const f32x4*)(asrc + 140);
    __syncthreads();

    for (int ks = 0; ks < 8; ++ks) {
        const int cur = ks & 1;
        if (ks < 7) {
            // barrier at end of prev iter guarantees buf[cur^1] is drained
            *(short8*)&As[cur ^ 1][arow][ac0]     = cvt8(r0, r1);
            *(short8*)&As[cur ^ 1][arow][ac0 + 8] = cvt8(r2, r3);
            if (ks < 6) {
                const float* nsrc = asrc + (size_t)(ks + 2) * 128;
                r0 = *(const f32x4*)(nsrc);
                r1 = *(const f32x4*)(nsrc + 4);
                r2 = *(const f32x4*)(nsrc + 8);
                r3 = *(const f32x4*)(nsrc + 12);
            }
        }
        #pragma unroll
        for (int kc = 0; kc < 4; ++kc) {
            short8 af0 = *(const short8*)&As[cur][l15][kc * 32 + lhi * 8];
            short8 af1 = *(const short8*)&As[cur][16 + l15][kc * 32 + lhi * 8];
            #pragma unroll
            for (int nj = 0; nj < 3; ++nj) {
                short8 bf = *(const short8*)(wtf + (size_t)((wn * 3 + nj) * 32 + ks * 4 + kc) * 512 + lane * 8);
                acc[0][nj] = __builtin_amdgcn_mfma_f32_16x16x32_bf16(af0, bf, acc[0][nj], 0, 0, 0);
                acc[1][nj] = __builtin_amdgcn_mfma_f32_16x16x32_bf16(af1, bf, acc[1][nj], 0, 0, 0);
            }
        }
        __syncthreads();
    }

    // epilogue: scatter into fragment-linear q/k/v (round-9 verified algebra)
    for (int mt = 0; mt < 2; ++mt) {
        const int growb = row0 + mt * 16 + lhi * 4;    // t = growb + r
        const int bI = growb >> 11;
        const int tloc = growb & 2047;
        for (int nj = 0; nj < 3; ++nj) {
            const int gcolb = wn * 48 + nj * 16;
            const int matid = gcolb >> 6;
            const int d0 = gcolb & 63;
            if (matid < 2) {
                u16* dst = matid == 0 ? qfl : kfl;
                const int g = tloc >> 4;
                const int lhid = ((d0 & 31) + l15) >> 3;
                const size_t base = ((size_t)(bI * 128 + g) * 2 + (d0 >> 5)) * 512
                                    + (size_t)lhid * 128 + (l15 & 7);
                for (int r = 0; r < 4; ++r)
                    dst[base + (size_t)(lhi * 4 + r) * 8] = bfu(acc[mt][nj][r]);
            } else {
                const int kt64 = tloc >> 6;
                const int tin = tloc & 63;
                const int kcv = tin >> 5;
                const int lhiv = (tin & 31) >> 3;
                const int e0 = tin & 7;
                const int dt = d0 >> 4;
                u16x4 pk;
                pk[0] = bfu(acc[mt][nj][0]); pk[1] = bfu(acc[mt][nj][1]);
                pk[2] = bfu(acc[mt][nj][2]); pk[3] = bfu(acc[mt][nj][3]);
                *(u16x4*)(vfl + ((size_t)((bI * 32 + kt64) * 4 + dt) * 2 + kcv) * 512
                              + (size_t)(lhiv * 16 + l15) * 8 + e0) = pk;
            }
        }
    }
}

// Flash attention, causal. Block-level split-K, 8 waves per 16-row q-tile
// (round-17 verified, byte-identical).
__global__ __launch_bounds__(512, 4) void attn_fwd(const u16* __restrict__ qfl,
                                                   const u16* __restrict__ kfl,
                                                   const u16* __restrict__ vfl,
                                                   float* __restrict__ out) {
    __shared__ float o_lds[8][16][68];
    __shared__ float ml_lds[8][2][16];
    __shared__ u16 pl[8][16][72];
    const int tid = threadIdx.x;
    const int lane = tid & 63;
    const int w = tid >> 6;           // 0..7
    const int l15 = lane & 15, lhi = lane >> 4;
    const int idx = (int)blockIdx.x;  // 0..1023
    const int qt = 127 - (idx >> 3);  // longest q-tiles dispatched first
    const int b = idx & 7;
    const int nkt = (qt >> 2) + 1;
    const int q0 = qt * 16;

    const u16* qb = qfl + (size_t)b * 131072;
    const u16* kb = kfl + (size_t)b * 131072;
    const u16* vb = vfl + (size_t)b * 131072;

    short8 qf[2];
    #pragma unroll
    for (int kc = 0; kc < 2; ++kc)
        qf[kc] = *(const short8*)(qb + ((size_t)(qt * 2 + kc) * 64 + lane) * 8);

    float m = -1e30f, lpart = 0.f;
    f32x4 o[4];
    for (int dt = 0; dt < 4; ++dt) o[dt] = f32x4{0.f, 0.f, 0.f, 0.f};

    for (int kbi = w; kbi < nkt; kbi += 8) {
        const int k0 = kbi * 64;
        short8 kf[2][4], vf[4][2];
        #pragma unroll
        for (int kc = 0; kc < 2; ++kc)
            #pragma unroll
            for (int kt = 0; kt < 4; ++kt)
                kf[kc][kt] = *(const short8*)(kb + ((size_t)((kbi * 4 + kt) * 2 + kc) * 64 + lane) * 8);
        #pragma unroll
        for (int dt = 0; dt < 4; ++dt)
            #pragma unroll
            for (int kc = 0; kc < 2; ++kc)
                vf[dt][kc] = *(const short8*)(vb + ((size_t)((kbi * 4 + dt) * 2 + kc) * 512 + lane * 8));

        f32x4 sacc[4];
        for (int kt = 0; kt < 4; ++kt) sacc[kt] = f32x4{0.f, 0.f, 0.f, 0.f};
        #pragma unroll
        for (int kc = 0; kc < 2; ++kc)
            #pragma unroll
            for (int kt = 0; kt < 4; ++kt)
                sacc[kt] = __builtin_amdgcn_mfma_f32_16x16x32_bf16(kf[kc][kt], qf[kc], sacc[kt], 0, 0, 0);

        if (kbi == nkt - 1) {             // diagonal: causal mask
            for (int kt = 0; kt < 4; ++kt)
                for (int r = 0; r < 4; ++r) {
                    int kg = k0 + kt * 16 + lhi * 4 + r;
                    if (kg > q0 + l15) sacc[kt][r] = -3.0e38f;
                }
        }
        f32x4 mx0, mx1;
        for (int e = 0; e < 4; ++e) {
            mx0[e] = fmaxf(sacc[0][e], sacc[1][e]);
            mx1[e] = fmaxf(sacc[2][e], sacc[3][e]);
        }
        float tmax = -3.0e38f;
        for (int e = 0; e < 4; ++e) tmax = fmaxf(tmax, fmaxf(mx0[e], mx1[e]));
        tmax = fmaxf(tmax, __shfl_xor(tmax, 16));
        tmax = fmaxf(tmax, __shfl_xor(tmax, 32));
        if (!__all(tmax <= m + 8.0f)) {   // defer-max (THR=8, log2 domain)
            float mnew = fmaxf(m, tmax);
            float corr = exp2f(m - mnew);
            m = mnew;
            lpart *= corr;
            for (int r = 0; r < 4; ++r) {
                float cr = __shfl(corr, lhi * 4 + r);
                for (int dt = 0; dt < 4; ++dt) o[dt][r] *= cr;
            }
        }
        float psum = 0.f;
        for (int kt = 0; kt < 4; ++kt)
            for (int r = 0; r < 4; ++r) {
                float p = exp2f(sacc[kt][r] - m);
                sacc[kt][r] = p;
                psum += p;
            }
        lpart += psum;
        for (int kt = 0; kt < 4; ++kt) {
            u16x4 pk;
            pk[0] = bfu(sacc[kt][0]); pk[1] = bfu(sacc[kt][1]);
            pk[2] = bfu(sacc[kt][2]); pk[3] = bfu(sacc[kt][3]);
            *(u16x4*)&pl[w][l15][kt * 16 + lhi * 4] = pk;
        }
        short8 pf[2];
        #pragma unroll
        for (int kc = 0; kc < 2; ++kc)
            pf[kc] = *(const short8*)&pl[w][l15][kc * 32 + lhi * 8];
        #pragma unroll
        for (int dt = 0; dt < 4; ++dt)
            #pragma unroll
            for (int kc = 0; kc < 2; ++kc)
                o[dt] = __builtin_amdgcn_mfma_f32_16x16x32_bf16(pf[kc], vf[dt][kc], o[dt], 0, 0, 0);
    }
    float lsum = lpart;
    lsum += __shfl_xor(lsum, 16);
    lsum += __shfl_xor(lsum, 32);

    for (int dt = 0; dt < 4; ++dt)
        for (int r = 0; r < 4; ++r)
            o_lds[w][lhi * 4 + r][dt * 16 + l15] = o[dt][r];
    if (lhi == 0) {
        ml_lds[w][0][l15] = m;
        ml_lds[w][1][l15] = lsum;
    }
    __syncthreads();

    float* ob = out + ((size_t)b * Tn + q0) * Hn;
    #pragma unroll
    for (int i = 0; i < 2; ++i) {
        const int e = tid + 512 * i;      // 0..1023
        const int row = e >> 6, d = e & 63;
        float M = -3.0e38f;
        #pragma unroll
        for (int ww = 0; ww < 8; ++ww) M = fmaxf(M, ml_lds[ww][0][row]);
        float L = 0.f, acc = 0.f;
        #pragma unroll
        for (int ww = 0; ww < 8; ++ww) {
            float wgt = exp2f(ml_lds[ww][0][row] - M);
            L += ml_lds[ww][1][row] * wgt;
            acc += o_lds[ww][row][d] * wgt;
        }
        ob[(size_t)row * Hn + d] = acc / L;
    }
}

extern "C" void kernel_launch(void* const* d_in, const int* in_sizes, int n_in,
                              void* d_out, int out_size, void* d_ws, size_t ws_size,
                              hipStream_t stream) {
    const float* x = (const float*)d_in[0];
    const float* Wq = (const float*)d_in[1];
    const float* Wk = (const float*)d_in[2];
    const float* Wv = (const float*)d_in[3];
    float* out = (float*)d_out;
    char* ws = (char*)d_ws;

    u16* wtf = (u16*)ws;                                   // 384 KB
    u16* qfl = (u16*)(ws + 196608 * 2);                    // 2 MB
    u16* kfl = qfl + (size_t)Bn * 131072;                  // 2 MB
    u16* vfl = kfl + (size_t)Bn * 131072;                  // 2 MB

    const float qscale = 0.04508422002778011f;  // C^-0.5 * log2(e)
    convert_w3<<<768, 256, 0, stream>>>(Wq, Wk, Wv, wtf, qscale);
    qkv_proj<<<Mrows / 32, 256, 0, stream>>>(x, wtf, qfl, kfl, vfl);
    attn_fwd<<<1024, 512, 0, stream>>>(qfl, kfl, vfl, out);
}